// Round 2
// baseline (193.753 us; speedup 1.0000x reference)
//
#include <hip/hip_runtime.h>
#include <math.h>

#define NUM_CLASSES 10

// ---- block reduction: wave shuffle (64) -> LDS across waves -> lane 0 ----
__device__ __forceinline__ double block_reduce_sum(double v, double* lds) {
    #pragma unroll
    for (int off = 32; off > 0; off >>= 1)
        v += __shfl_down(v, off, 64);
    int lane = threadIdx.x & 63;
    int wid  = threadIdx.x >> 6;
    int nw   = blockDim.x >> 6;
    if (lane == 0) lds[wid] = v;
    __syncthreads();
    if (wid == 0) {
        v = (lane < nw) ? lds[lane] : 0.0;
        #pragma unroll
        for (int off = 4; off > 0; off >>= 1)
            v += __shfl_down(v, off, 64);
    }
    return v;
}

__device__ __forceinline__ float relu_dot4(float4 a, float4 b) {
    float v;
    v  = fmaxf(a.x, 0.f) * fmaxf(b.x, 0.f);
    v += fmaxf(a.y, 0.f) * fmaxf(b.y, 0.f);
    v += fmaxf(a.z, 0.f) * fmaxf(b.z, 0.f);
    v += fmaxf(a.w, 0.f) * fmaxf(b.w, 0.f);
    return v;
}

// One fused kernel: focal (first B threads) + spatial (8 lanes per edge) +
// last-block finalize. acc[0]=focal sum, acc[1]=spatial sum, ctr at acc+2.
__global__ __launch_bounds__(256) void fused_kernel(
    const float*  __restrict__ logits,
    const int*    __restrict__ targets,
    const int*    __restrict__ tissue,
    const float*  __restrict__ cw,
    const float*  __restrict__ tw,
    const float4* __restrict__ S4,     // S as float4 rows: 8 per node
    const float2* __restrict__ pos,
    const int*    __restrict__ src_idx,
    const int*    __restrict__ dst_idx,
    int B, int E,
    double*       __restrict__ acc,
    unsigned*     __restrict__ ctr,
    float*        __restrict__ out) {

    __shared__ double lds_f[4];
    __shared__ double lds_s[4];

    int gtid = blockIdx.x * blockDim.x + threadIdx.x;

    // ---- focal loss: one thread per batch row (first B threads) ----
    double fl = 0.0;
    if (gtid < B) {
        const float* row = logits + (size_t)gtid * NUM_CLASSES;
        float l[NUM_CLASSES];
        float m = -INFINITY;
        #pragma unroll
        for (int c = 0; c < NUM_CLASSES; ++c) { l[c] = row[c]; m = fmaxf(m, l[c]); }
        float s = 0.f;
        #pragma unroll
        for (int c = 0; c < NUM_CLASSES; ++c) s += expf(l[c] - m);
        int   t  = targets[gtid];
        float lp = l[t] - m - logf(s);         // log p_t
        float p  = expf(lp);
        float om = 1.f - p;
        float w  = om * om * cw[t] * tw[tissue[gtid]];
        fl = (double)(-w * lp);
    }

    // ---- spatial: 8-lane cooperative edge processing, unroll x2 ----
    int sub     = threadIdx.x & 7;          // float4 chunk within the 32-wide row
    int group   = gtid >> 3;                // edge-group id
    int ngroups = (gridDim.x * blockDim.x) >> 3;
    double sp = 0.0;
    for (int e0 = group; e0 < E; e0 += 2 * ngroups) {
        int  e1  = e0 + ngroups;
        bool v1  = e1 < E;
        int  e1s = v1 ? e1 : e0;

        int sA = src_idx[e0],  dA = dst_idx[e0];
        int sB = src_idx[e1s], dB = dst_idx[e1s];

        float4 a0 = S4[(size_t)sA * 8 + sub];
        float4 b0 = S4[(size_t)dA * 8 + sub];
        float4 a1 = S4[(size_t)sB * 8 + sub];
        float4 b1 = S4[(size_t)dB * 8 + sub];

        float2 psA = pos[sA], pdA = pos[dA];
        float2 psB = pos[sB], pdB = pos[dB];

        float w0 = relu_dot4(a0, b0);
        float w1 = relu_dot4(a1, b1);

        // reduce across the 8 lanes of the group
        w0 += __shfl_xor(w0, 1); w0 += __shfl_xor(w0, 2); w0 += __shfl_xor(w0, 4);
        w1 += __shfl_xor(w1, 1); w1 += __shfl_xor(w1, 2); w1 += __shfl_xor(w1, 4);

        if (sub == 0) {
            float dxA = psA.x - pdA.x, dyA = psA.y - pdA.y;
            sp += (double)(w0 * (dxA * dxA + dyA * dyA));
            if (v1) {
                float dxB = psB.x - pdB.x, dyB = psB.y - pdB.y;
                sp += (double)(w1 * (dxB * dxB + dyB * dyB));
            }
        }
    }

    double bs_f = block_reduce_sum(fl, lds_f);
    double bs_s = block_reduce_sum(sp, lds_s);

    if (threadIdx.x == 0) {
        atomicAdd(&acc[0], bs_f);
        atomicAdd(&acc[1], bs_s);
        __threadfence();
        unsigned done = atomicAdd(ctr, 1u);
        if (done == gridDim.x - 1) {
            __threadfence();
            double cs = atomicAdd(&acc[0], 0.0);   // atomic read (device scope)
            double ss = atomicAdd(&acc[1], 0.0);
            float cls = (float)(cs / (double)B);
            float spv = (float)(0.01 * ss / (double)E);
            out[0] = cls + spv;
            out[1] = cls;
            out[2] = spv;
        }
    }
}

extern "C" void kernel_launch(void* const* d_in, const int* in_sizes, int n_in,
                              void* d_out, int out_size, void* d_ws, size_t ws_size,
                              hipStream_t stream) {
    const float* logits  = (const float*)d_in[0];
    const int*   targets = (const int*)  d_in[1];
    const float* S       = (const float*)d_in[2];
    const float* pos     = (const float*)d_in[3];
    const int*   edge    = (const int*)  d_in[4];
    const int*   tissue  = (const int*)  d_in[5];
    const float* cw      = (const float*)d_in[6];
    const float* tw      = (const float*)d_in[7];
    float* out = (float*)d_out;

    int B = in_sizes[1];
    int E = in_sizes[4] / 2;

    double*   acc = (double*)d_ws;                 // acc[0], acc[1]
    unsigned* ctr = (unsigned*)((char*)d_ws + 16); // completion counter
    hipMemsetAsync(d_ws, 0, 24, stream);

    const int GRID = 2048;
    fused_kernel<<<GRID, 256, 0, stream>>>(
        logits, targets, tissue, cw, tw,
        (const float4*)S, (const float2*)pos, edge, edge + E,
        B, E, acc, ctr, out);
}

// Round 3
// 166.488 us; speedup vs baseline: 1.1638x; 1.1638x over previous
//
#include <hip/hip_runtime.h>
#include <hip/hip_fp16.h>
#include <math.h>

#define NUM_CLASSES 10

// ---- block reduction: wave shuffle (64) -> LDS across waves -> lane 0 ----
__device__ __forceinline__ double block_reduce_sum(double v, double* lds) {
    #pragma unroll
    for (int off = 32; off > 0; off >>= 1)
        v += __shfl_down(v, off, 64);
    int lane = threadIdx.x & 63;
    int wid  = threadIdx.x >> 6;
    int nw   = blockDim.x >> 6;
    if (lane == 0) lds[wid] = v;
    __syncthreads();
    if (wid == 0) {
        v = (lane < nw) ? lds[lane] : 0.0;
        #pragma unroll
        for (int off = 4; off > 0; off >>= 1)
            v += __shfl_down(v, off, 64);
    }
    return v;
}

// dot of 8 fp16 pairs held in two float4 register images
__device__ __forceinline__ float hdot8(float4 a, float4 b) {
    const __half2* ah = reinterpret_cast<const __half2*>(&a);
    const __half2* bh = reinterpret_cast<const __half2*>(&b);
    float d = 0.f;
    #pragma unroll
    for (int j = 0; j < 4; ++j) {
        float2 x = __half22float2(ah[j]);
        float2 y = __half22float2(bh[j]);
        d = fmaf(x.x, y.x, d);
        d = fmaf(x.y, y.y, d);
    }
    return d;
}

__device__ __forceinline__ float relu_dot4(float4 a, float4 b) {
    float v;
    v  = fmaxf(a.x, 0.f) * fmaxf(b.x, 0.f);
    v += fmaxf(a.y, 0.f) * fmaxf(b.y, 0.f);
    v += fmaxf(a.z, 0.f) * fmaxf(b.z, 0.f);
    v += fmaxf(a.w, 0.f) * fmaxf(b.w, 0.f);
    return v;
}

__device__ __forceinline__ double focal_term(
    const float* __restrict__ logits, const int* __restrict__ targets,
    const int* __restrict__ tissue, const float* __restrict__ cw,
    const float* __restrict__ tw, int r) {
    const float* row = logits + (size_t)r * NUM_CLASSES;
    float l[NUM_CLASSES];
    float m = -INFINITY;
    #pragma unroll
    for (int c = 0; c < NUM_CLASSES; ++c) { l[c] = row[c]; m = fmaxf(m, l[c]); }
    float s = 0.f;
    #pragma unroll
    for (int c = 0; c < NUM_CLASSES; ++c) s += expf(l[c] - m);
    int   t  = targets[r];
    float lp = l[t] - m - logf(s);
    float p  = expf(lp);
    float om = 1.f - p;
    float w  = om * om * cw[t] * tw[tissue[r]];
    return (double)(-w * lp);
}

// ---- pack relu(S) fp32 -> fp16 rows (halves working set: 6.4 -> 3.2 MB) ----
__global__ void pack_kernel(const float4* __restrict__ S4,
                            float2* __restrict__ R2, int n4) {
    for (int i = blockIdx.x * blockDim.x + threadIdx.x; i < n4;
         i += gridDim.x * blockDim.x) {
        float4 v = S4[i];
        union { __half2 h[2]; float2 f; } u;
        u.h[0] = __floats2half2_rn(fmaxf(v.x, 0.f), fmaxf(v.y, 0.f));
        u.h[1] = __floats2half2_rn(fmaxf(v.z, 0.f), fmaxf(v.w, 0.f));
        R2[i] = u.f;
    }
}

__device__ __forceinline__ void finalize_and_store(
    double fl, double sp, double* lds_f, double* lds_s,
    double* __restrict__ acc, unsigned* __restrict__ ctr,
    float* __restrict__ out, int B, int E) {
    double bs_f = block_reduce_sum(fl, lds_f);
    double bs_s = block_reduce_sum(sp, lds_s);
    if (threadIdx.x == 0) {
        atomicAdd(&acc[0], bs_f);
        atomicAdd(&acc[1], bs_s);
        __threadfence();
        unsigned done = atomicAdd(ctr, 1u);
        if (done == gridDim.x - 1) {
            __threadfence();
            double cs = atomicAdd(&acc[0], 0.0);
            double ss = atomicAdd(&acc[1], 0.0);
            float cls = (float)(cs / (double)B);
            float spv = (float)(0.01 * ss / (double)E);
            out[0] = cls + spv;
            out[1] = cls;
            out[2] = spv;
        }
    }
}

// ---- main fused kernel, fp16 rows, 4 lanes per edge, unroll x4 ----
__global__ __launch_bounds__(256) void fused_fp16_kernel(
    const float*  __restrict__ logits,
    const int*    __restrict__ targets,
    const int*    __restrict__ tissue,
    const float*  __restrict__ cw,
    const float*  __restrict__ tw,
    const float4* __restrict__ R4,     // fp16 rows: 4 float4 per node
    const float2* __restrict__ pos,
    const int*    __restrict__ src_idx,
    const int*    __restrict__ dst_idx,
    int B, int E,
    double*       __restrict__ acc,
    unsigned*     __restrict__ ctr,
    float*        __restrict__ out) {

    __shared__ double lds_f[4];
    __shared__ double lds_s[4];
    int gtid = blockIdx.x * blockDim.x + threadIdx.x;

    double fl = 0.0;
    if (gtid < B) fl = focal_term(logits, targets, tissue, cw, tw, gtid);

    int sub     = threadIdx.x & 3;
    int quad    = gtid >> 2;
    int nquads  = (gridDim.x * blockDim.x) >> 2;
    double sp = 0.0;

    for (int e0 = quad; e0 < E; e0 += 4 * nquads) {
        int e1 = e0 + nquads, e2 = e0 + 2 * nquads, e3 = e0 + 3 * nquads;
        float m1 = (e1 < E) ? 1.f : 0.f;
        float m2 = (e2 < E) ? 1.f : 0.f;
        float m3 = (e3 < E) ? 1.f : 0.f;
        int e1c = (e1 < E) ? e1 : 0;
        int e2c = (e2 < E) ? e2 : 0;
        int e3c = (e3 < E) ? e3 : 0;

        int s0 = src_idx[e0],  d0 = dst_idx[e0];
        int s1 = src_idx[e1c], d1 = dst_idx[e1c];
        int s2 = src_idx[e2c], d2i = dst_idx[e2c];
        int s3 = src_idx[e3c], d3 = dst_idx[e3c];

        // hoist all gathers: 8 row chunks + 8 positions in flight
        float4 a0 = R4[(size_t)s0 * 4 + sub];
        float4 b0 = R4[(size_t)d0 * 4 + sub];
        float4 a1 = R4[(size_t)s1 * 4 + sub];
        float4 b1 = R4[(size_t)d1 * 4 + sub];
        float4 a2 = R4[(size_t)s2 * 4 + sub];
        float4 b2 = R4[(size_t)d2i * 4 + sub];
        float4 a3 = R4[(size_t)s3 * 4 + sub];
        float4 b3 = R4[(size_t)d3 * 4 + sub];

        float2 ps0 = pos[s0], pd0 = pos[d0];
        float2 ps1 = pos[s1], pd1 = pos[d1];
        float2 ps2 = pos[s2], pd2 = pos[d2i];
        float2 ps3 = pos[s3], pd3 = pos[d3];

        float w0 = hdot8(a0, b0);
        float w1 = hdot8(a1, b1);
        float w2 = hdot8(a2, b2);
        float w3 = hdot8(a3, b3);

        // butterfly within the quad -> every lane holds the full 32-dot
        w0 += __shfl_xor(w0, 1); w0 += __shfl_xor(w0, 2);
        w1 += __shfl_xor(w1, 1); w1 += __shfl_xor(w1, 2);
        w2 += __shfl_xor(w2, 1); w2 += __shfl_xor(w2, 2);
        w3 += __shfl_xor(w3, 1); w3 += __shfl_xor(w3, 2);

        // all 4 lanes accumulate (x4 total, corrected by 0.25 below)
        float dx, dy;
        dx = ps0.x - pd0.x; dy = ps0.y - pd0.y;
        sp += (double)(w0 * (dx * dx + dy * dy));
        dx = ps1.x - pd1.x; dy = ps1.y - pd1.y;
        sp += (double)(w1 * (dx * dx + dy * dy) * m1);
        dx = ps2.x - pd2.x; dy = ps2.y - pd2.y;
        sp += (double)(w2 * (dx * dx + dy * dy) * m2);
        dx = ps3.x - pd3.x; dy = ps3.y - pd3.y;
        sp += (double)(w3 * (dx * dx + dy * dy) * m3);
    }
    sp *= 0.25;

    finalize_and_store(fl, sp, lds_f, lds_s, acc, ctr, out, B, E);
}

// ---- fallback: fp32 rows direct (if ws can't hold the pack buffer) ----
__global__ __launch_bounds__(256) void fused_fp32_kernel(
    const float*  __restrict__ logits,
    const int*    __restrict__ targets,
    const int*    __restrict__ tissue,
    const float*  __restrict__ cw,
    const float*  __restrict__ tw,
    const float4* __restrict__ S4,     // fp32 rows: 8 float4 per node
    const float2* __restrict__ pos,
    const int*    __restrict__ src_idx,
    const int*    __restrict__ dst_idx,
    int B, int E,
    double*       __restrict__ acc,
    unsigned*     __restrict__ ctr,
    float*        __restrict__ out) {

    __shared__ double lds_f[4];
    __shared__ double lds_s[4];
    int gtid = blockIdx.x * blockDim.x + threadIdx.x;

    double fl = 0.0;
    if (gtid < B) fl = focal_term(logits, targets, tissue, cw, tw, gtid);

    int sub    = threadIdx.x & 3;          // lane covers chunks 2*sub, 2*sub+1
    int quad   = gtid >> 2;
    int nquads = (gridDim.x * blockDim.x) >> 2;
    double sp = 0.0;

    for (int e0 = quad; e0 < E; e0 += 2 * nquads) {
        int e1 = e0 + nquads;
        float m1 = (e1 < E) ? 1.f : 0.f;
        int e1c = (e1 < E) ? e1 : 0;

        int s0 = src_idx[e0],  d0 = dst_idx[e0];
        int s1 = src_idx[e1c], d1 = dst_idx[e1c];

        const float4* r;
        r = S4 + (size_t)s0 * 8 + sub * 2; float4 a0l = r[0], a0h = r[1];
        r = S4 + (size_t)d0 * 8 + sub * 2; float4 b0l = r[0], b0h = r[1];
        r = S4 + (size_t)s1 * 8 + sub * 2; float4 a1l = r[0], a1h = r[1];
        r = S4 + (size_t)d1 * 8 + sub * 2; float4 b1l = r[0], b1h = r[1];

        float2 ps0 = pos[s0], pd0 = pos[d0];
        float2 ps1 = pos[s1], pd1 = pos[d1];

        float w0 = relu_dot4(a0l, b0l) + relu_dot4(a0h, b0h);
        float w1 = relu_dot4(a1l, b1l) + relu_dot4(a1h, b1h);
        w0 += __shfl_xor(w0, 1); w0 += __shfl_xor(w0, 2);
        w1 += __shfl_xor(w1, 1); w1 += __shfl_xor(w1, 2);

        float dx, dy;
        dx = ps0.x - pd0.x; dy = ps0.y - pd0.y;
        sp += (double)(w0 * (dx * dx + dy * dy));
        dx = ps1.x - pd1.x; dy = ps1.y - pd1.y;
        sp += (double)(w1 * (dx * dx + dy * dy) * m1);
    }
    sp *= 0.25;

    finalize_and_store(fl, sp, lds_f, lds_s, acc, ctr, out, B, E);
}

extern "C" void kernel_launch(void* const* d_in, const int* in_sizes, int n_in,
                              void* d_out, int out_size, void* d_ws, size_t ws_size,
                              hipStream_t stream) {
    const float* logits  = (const float*)d_in[0];
    const int*   targets = (const int*)  d_in[1];
    const float* S       = (const float*)d_in[2];
    const float* pos     = (const float*)d_in[3];
    const int*   edge    = (const int*)  d_in[4];
    const int*   tissue  = (const int*)  d_in[5];
    const float* cw      = (const float*)d_in[6];
    const float* tw      = (const float*)d_in[7];
    float* out = (float*)d_out;

    int B = in_sizes[1];
    int E = in_sizes[4] / 2;
    int nS = in_sizes[2];                    // N_NODES * 32

    double*   acc = (double*)d_ws;           // acc[0]=focal, acc[1]=spatial
    unsigned* ctr = (unsigned*)((char*)d_ws + 16);
    hipMemsetAsync(d_ws, 0, 24, stream);

    size_t pack_bytes = (size_t)nS * sizeof(__half);
    const int GRID = 1600;                   // nquads = 102400

    if (ws_size >= 256 + pack_bytes) {
        __half* R = (__half*)((char*)d_ws + 256);
        int n4 = nS / 4;
        pack_kernel<<<(n4 + 255) / 256, 256, 0, stream>>>(
            (const float4*)S, (float2*)R, n4);
        fused_fp16_kernel<<<GRID, 256, 0, stream>>>(
            logits, targets, tissue, cw, tw,
            (const float4*)R, (const float2*)pos, edge, edge + E,
            B, E, acc, ctr, out);
    } else {
        fused_fp32_kernel<<<GRID, 256, 0, stream>>>(
            logits, targets, tissue, cw, tw,
            (const float4*)S, (const float2*)pos, edge, edge + E,
            B, E, acc, ctr, out);
    }
}